// Round 3
// baseline (268.934 us; speedup 1.0000x reference)
//
#include <hip/hip_runtime.h>

// StackLSTMCell: B=256, IN=256, H=256, L=2, S=128 (SLOTS=129). All f32.
//
// Structure (copy = stack passthrough, rides every phase):
//   K1 gemm_copy_k : gemm0 partials (split-K) + copy hid[0..H1)
//   K2 act0_copy_k : act0 (sums partials+bias) + copy hid tail + cel head
//   K3 gemm_copy_k : gemm1 partials + copy cel rest
//   K4 slot_k      : write pos+1 slot in both out-stacks (sums layer-1
//                    partials+bias inline) + finalize h_out/c_out. No copy
//                    here (would race with slot writes).
//
// GEMM redesign vs previous round: BM=32 x BN=128, 4x4 register tile
// (16 FMA per 2 ds_read_b128 -> ~3x less LDS-pipe pressure), split-K x KS
// (KS=4 -> 256 blocks, 1/CU) with partial sums finished by the consumers.

static __device__ __forceinline__ float sigf(float x) {
    return 1.0f / (1.0f + __expf(-x));
}
static __device__ __forceinline__ float tanh_fast(float x) {
    return 2.0f / (1.0f + __expf(-2.0f * x)) - 1.0f;
}

#define NV4_PER_STACK 4227072     // 129*256*256*2/4 float4 per stack
#define STACK_ELEMS   16908288    // 129*256*256*2

// grid-stride passthrough copy over up to two spans; blocks [cb0, grid)
static __device__ __forceinline__ void copy_spans(
    int cb0, int nb1,
    const float4* __restrict__ s1, float4* __restrict__ d1, int n1,
    const float4* __restrict__ s2, float4* __restrict__ d2, int n2)
{
    int cb = blockIdx.x - cb0;
    int ncopy = gridDim.x - cb0;
    if (cb < nb1) {
        int stride = nb1 * 256;
        for (int i = cb * 256 + threadIdx.x; i < n1; i += stride)
            d1[i] = s1[i];
    } else if (n2 > 0) {
        int nb2 = ncopy - nb1;
        int stride = nb2 * 256;
        for (int i = (cb - nb1) * 256 + threadIdx.x; i < n2; i += stride)
            d2[i] = s2[i];
    }
}

// ---------------------------------------------------------------------------
// Split-K partial GEMM: gpart[ks][b][j] = A[b, k0..k0+512/nks) . W[j, same]
// A row b: k<256 -> a_lo[b*256+k]; k>=256 -> a_hi gather (stride 2) at pos[b].
// W row j: k<256 -> wih[j][k];     k>=256 -> whh[j][k-256].
// Block: 256 thr, tile BM=32 x BN=128, thread-tile 4x4.
// Compute blocks [0, 64*nks); the rest are copy workers.
__global__ __launch_bounds__(256) void gemm_copy_k(
    const float* __restrict__ a_lo,
    const float* __restrict__ a_hi,
    const int*   __restrict__ pos,
    const float* __restrict__ wih,
    const float* __restrict__ whh,
    float* __restrict__ gpart, int nks,
    int nb1, const float4* __restrict__ cs1, float4* __restrict__ cd1, int cn1,
    const float4* __restrict__ cs2, float4* __restrict__ cd2, int cn2)
{
    int ncomp = nks << 6;              // 64 * nks compute blocks
    if ((int)blockIdx.x >= ncomp) {
        copy_spans(ncomp, nb1, cs1, cd1, cn1, cs2, cd2, cn2);
        return;
    }

    __shared__ float As[32][36];       // [k][b], 36 keeps float4 16B-aligned
    __shared__ float Ws[32][132];      // [k][j], 132*4B = 528 (16B-aligned)

    int t   = threadIdx.x;
    int ks  = blockIdx.x >> 6;
    int tb  = blockIdx.x & 63;
    int bm0 = (tb >> 3) << 5;          // 8 b-tiles of 32
    int jt0 = (tb & 7) << 7;           // 8 j-tiles of 128
    int kspan = 512 / nks;
    int k0  = ks * kspan;
    int nsub = kspan >> 5;             // K-subtiles of 32

    // staging ids
    int arow = t >> 3;                 // 0..31
    int ak4  = (t & 7) << 2;           // 0,4,..,28
    int ab   = bm0 + arow;
    int ap   = pos[ab];
    int wrow = t >> 1;                 // 0..127
    int wk   = (t & 1) << 4;           // 0 or 16
    int wj   = jt0 + wrow;
    // compute ids
    int tx = t & 31, ty = t >> 5;

    float acc[4][4] = {{0.f}};
    for (int s = 0; s < nsub; ++s) {
        int kb = k0 + (s << 5);
        // ---- stage A (32 b x 32 k), k-major transposed into LDS
        {
            int kg = kb + ak4;         // 4-aligned; never straddles 256
            if (kg < 256) {
                float4 v = *(const float4*)&a_lo[ab * 256 + kg];
                As[ak4 + 0][arow] = v.x;
                As[ak4 + 1][arow] = v.y;
                As[ak4 + 2][arow] = v.z;
                As[ak4 + 3][arow] = v.w;
            } else {
                const float* ah = a_hi + ((ap * 256 + ab) * 256 + (kg - 256)) * 2;
                As[ak4 + 0][arow] = ah[0];
                As[ak4 + 1][arow] = ah[2];
                As[ak4 + 2][arow] = ah[4];
                As[ak4 + 3][arow] = ah[6];
            }
        }
        // ---- stage W (128 j x 32 k), transposed on staging
        {
            int kg = kb + wk;          // 16-aligned; never straddles 256
            const float* ws = (kg < 256) ? &wih[wj * 256 + kg]
                                         : &whh[wj * 256 + kg - 256];
            #pragma unroll
            for (int i = 0; i < 4; ++i) {
                float4 v = *(const float4*)(ws + i * 4);
                Ws[wk + i * 4 + 0][wrow] = v.x;
                Ws[wk + i * 4 + 1][wrow] = v.y;
                Ws[wk + i * 4 + 2][wrow] = v.z;
                Ws[wk + i * 4 + 3][wrow] = v.w;
            }
        }
        __syncthreads();
        #pragma unroll
        for (int k = 0; k < 32; ++k) {
            float4 av = *(const float4*)&As[k][ty << 2];
            float4 wv = *(const float4*)&Ws[k][tx << 2];
            float w0 = wv.x, w1 = wv.y, w2 = wv.z, w3 = wv.w;
            acc[0][0] = fmaf(av.x, w0, acc[0][0]);
            acc[0][1] = fmaf(av.x, w1, acc[0][1]);
            acc[0][2] = fmaf(av.x, w2, acc[0][2]);
            acc[0][3] = fmaf(av.x, w3, acc[0][3]);
            acc[1][0] = fmaf(av.y, w0, acc[1][0]);
            acc[1][1] = fmaf(av.y, w1, acc[1][1]);
            acc[1][2] = fmaf(av.y, w2, acc[1][2]);
            acc[1][3] = fmaf(av.y, w3, acc[1][3]);
            acc[2][0] = fmaf(av.z, w0, acc[2][0]);
            acc[2][1] = fmaf(av.z, w1, acc[2][1]);
            acc[2][2] = fmaf(av.z, w2, acc[2][2]);
            acc[2][3] = fmaf(av.z, w3, acc[2][3]);
            acc[3][0] = fmaf(av.w, w0, acc[3][0]);
            acc[3][1] = fmaf(av.w, w1, acc[3][1]);
            acc[3][2] = fmaf(av.w, w2, acc[3][2]);
            acc[3][3] = fmaf(av.w, w3, acc[3][3]);
        }
        __syncthreads();
    }
    float* gp = gpart + ks * 262144 + (bm0 + (ty << 2)) * 1024 + jt0 + (tx << 2);
    #pragma unroll
    for (int i = 0; i < 4; ++i) {
        float4 r;
        r.x = acc[i][0]; r.y = acc[i][1]; r.z = acc[i][2]; r.w = acc[i][3];
        *(float4*)&gp[i * 1024] = r;
    }
}

// ---------------------------------------------------------------------------
// Layer-0 activation: sum split-K partials + biases, gate order i,f,g,o.
__global__ __launch_bounds__(256) void act0_copy_k(
    const float* __restrict__ gpart, int nks,
    const float* __restrict__ cel,
    const int*   __restrict__ pos,
    const float* __restrict__ bih, const float* __restrict__ bhh,
    float* __restrict__ h0f, float* __restrict__ c0f,
    int nb1, const float4* __restrict__ cs1, float4* __restrict__ cd1, int cn1,
    const float4* __restrict__ cs2, float4* __restrict__ cd2, int cn2)
{
    if (blockIdx.x >= 256) {
        copy_spans(256, nb1, cs1, cd1, cn1, cs2, cd2, cn2);
        return;
    }
    int e = blockIdx.x * 256 + threadIdx.x;   // 65536 = B*H
    int b = e >> 8, h = e & 255;
    float gi = bih[h]       + bhh[h];
    float gf = bih[256 + h] + bhh[256 + h];
    float gg = bih[512 + h] + bhh[512 + h];
    float go = bih[768 + h] + bhh[768 + h];
    const float* gp = gpart + b * 1024 + h;
    for (int ks = 0; ks < nks; ++ks, gp += 262144) {
        gi += gp[0]; gf += gp[256]; gg += gp[512]; go += gp[768];
    }
    float cin = cel[((pos[b] * 256 + b) * 256 + h) * 2];   // l=0
    float c  = sigf(gf) * cin + sigf(gi) * tanh_fast(gg);
    h0f[e] = sigf(go) * tanh_fast(c);
    c0f[e] = c;
}

// ---------------------------------------------------------------------------
// Layer-1 activation from split-K partials + biases.
static __device__ __forceinline__ void lstm1p(
    const float* __restrict__ gpart, int nks,
    const float* __restrict__ bih, const float* __restrict__ bhh,
    const float* __restrict__ cel,
    int p, int b, int h, float& hv, float& cv)
{
    float gi = bih[h]       + bhh[h];
    float gf = bih[256 + h] + bhh[256 + h];
    float gg = bih[512 + h] + bhh[512 + h];
    float go = bih[768 + h] + bhh[768 + h];
    const float* gp = gpart + b * 1024 + h;
    for (int ks = 0; ks < nks; ++ks, gp += 262144) {
        gi += gp[0]; gf += gp[256]; gg += gp[512]; go += gp[768];
    }
    float cin = cel[((p * 256 + b) * 256 + h) * 2 + 1];    // l=1
    cv = sigf(gf) * cin + sigf(gi) * tanh_fast(gg);
    hv = sigf(go) * tanh_fast(cv);
}

// Write freshly-computed pos+1 slot into both output stacks (overwrites the
// stale passthrough) + one finalize block for h_out/c_out.
__global__ __launch_bounds__(256) void slot_k(
    const float* __restrict__ hid, const float* __restrict__ cel,
    const int* __restrict__ pos, const int* __restrict__ op,
    const float* __restrict__ h0f, const float* __restrict__ c0f,
    const float* __restrict__ gpart, int nks,
    const float* __restrict__ bih, const float* __restrict__ bhh,
    float* __restrict__ out)
{
    if (blockIdx.x == 256) {
        // finalize: h_out (1,B,L) at out[0..511], c_out at out[512..1023]
        int b = threadIdx.x;
        int o = op[b];
        int p = pos[b];
        float h0v, h1v, c0v, c1v;
        if (o == 1) {            // new_pos == pos+1: freshly computed slot
            h0v = h0f[b * 256 + 255];
            c0v = c0f[b * 256 + 255];
            lstm1p(gpart, nks, bih, bhh, cel, p, b, 255, h1v, c1v);
        } else {                 // untouched slot: passthrough from input
            int base2 = (((p + o) * 256 + b) * 256 + 255) * 2;
            h0v = hid[base2]; h1v = hid[base2 + 1];
            c0v = cel[base2]; c1v = cel[base2 + 1];
        }
        out[b * 2]           = h0v;
        out[b * 2 + 1]       = h1v;
        out[512 + b * 2]     = c0v;
        out[512 + b * 2 + 1] = c1v;
        return;
    }
    int v = blockIdx.x * 256 + threadIdx.x;   // 0..65535 float4 of slot data
    bool is_cell = v >= 32768;
    int vv = v & 32767;
    int b = vv >> 7;            // 128 float4 per b-plane within a slot
    int q = vv & 127;           // elems (h=2q..2q+1, l=0..1)
    int p = pos[b];
    int h = q * 2;
    float h1a, c1a, h1b, c1b;
    lstm1p(gpart, nks, bih, bhh, cel, p, b, h,     h1a, c1a);
    lstm1p(gpart, nks, bih, bhh, cel, p, b, h + 1, h1b, c1b);
    float4 val;
    if (is_cell) {
        val.x = c0f[b * 256 + h];     val.y = c1a;
        val.z = c0f[b * 256 + h + 1]; val.w = c1b;
    } else {
        val.x = h0f[b * 256 + h];     val.y = h1a;
        val.z = h0f[b * 256 + h + 1]; val.w = h1b;
    }
    float4* dst = (float4*)(out + 1024 + (is_cell ? STACK_ELEMS : 0));
    dst[(p + 1) * 32768 + b * 128 + q] = val;
}

// ---------------------------------------------------------------------------
extern "C" void kernel_launch(void* const* d_in, const int* in_sizes, int n_in,
                              void* d_out, int out_size, void* d_ws, size_t ws_size,
                              hipStream_t stream) {
    const float* x    = (const float*)d_in[0];
    const float* hid  = (const float*)d_in[1];
    const float* cel  = (const float*)d_in[2];
    const float* wih0 = (const float*)d_in[3];
    const float* whh0 = (const float*)d_in[4];
    const float* bih0 = (const float*)d_in[5];
    const float* bhh0 = (const float*)d_in[6];
    const float* wih1 = (const float*)d_in[7];
    const float* whh1 = (const float*)d_in[8];
    const float* bih1 = (const float*)d_in[9];
    const float* bhh1 = (const float*)d_in[10];
    const int* op  = (const int*)d_in[11];
    const int* pos = (const int*)d_in[12];
    float* out = (float*)d_out;

    // workspace: gpart KS x 256x1024 + h0f/c0f 256x256 each (f32)
    size_t need4 = (size_t)(4 * 262144 + 2 * 65536) * 4;
    size_t need2 = (size_t)(2 * 262144 + 2 * 65536) * 4;
    int KS = (ws_size >= need4) ? 4 : (ws_size >= need2 ? 2 : 1);
    float* gpart = (float*)d_ws;
    float* h0f   = gpart + (size_t)KS * 262144;
    float* c0f   = h0f + 65536;

    const float4* hid_in  = (const float4*)hid;
    const float4* cel_in  = (const float4*)cel;
    float4*       hid_out = (float4*)(out + 1024);
    float4*       cel_out = (float4*)(out + 1024 + STACK_ELEMS);

    // copy partition (float4 units): balance walls of K1/K2/K3 at ~15us
    const int H1 = 2800000;                  // hid share in K1
    const int C2 = 1372928;                  // cel head in K2
    const int NCOPY = 2048;
    int n2a = NV4_PER_STACK - H1;            // hid tail in K2 (1427072)
    int nb1_2 = (int)((long long)NCOPY * n2a / (n2a + C2));

    // K1: gemm0 partials + hid[0..H1)
    gemm_copy_k<<<64 * KS + NCOPY, 256, 0, stream>>>(
        x, hid, pos, wih0, whh0, gpart, KS,
        NCOPY, hid_in, hid_out, H1,
        (const float4*)0, (float4*)0, 0);
    // K2: act0 + hid tail + cel head
    act0_copy_k<<<256 + NCOPY, 256, 0, stream>>>(
        gpart, KS, cel, pos, bih0, bhh0, h0f, c0f,
        nb1_2, hid_in + H1, hid_out + H1, n2a,
        cel_in, cel_out, C2);
    // K3: gemm1 partials (reuses gpart) + cel rest
    gemm_copy_k<<<64 * KS + NCOPY, 256, 0, stream>>>(
        h0f, hid + 1, pos, wih1, whh1, gpart, KS,
        NCOPY, cel_in + C2, cel_out + C2, NV4_PER_STACK - C2,
        (const float4*)0, (float4*)0, 0);
    // K4: pos+1 slot overwrite + finalize (no copy here: would race slots)
    slot_k<<<257, 256, 0, stream>>>(
        hid, cel, pos, op, h0f, c0f, gpart, KS, bih1, bhh1, out);
}